// Round 11
// baseline (606.453 us; speedup 1.0000x reference)
//
#include <hip/hip_runtime.h>
#include <hip/hip_bf16.h>

// GraphStack: 3x (GCNConv -> GraphNorm), N=100000, E=3.2M, D_IN=128, C=64.
//
// Round 11:
//  - gemm2 LDS fix: W stored row-major Wl[k][64], read as 4x ds_read_b32
//    (bank = c%32, 2-way = free) instead of b128 from [c][4] (8-way conflict,
//    2.8M conflict cycles measured). x reads stay wave-uniform broadcasts.
//  - bf16 staging writes vectorized (float4).
//  - Rest identical to round 10: 8-lane-group k_pull with 3-4 nodes/slot,
//    bf16 agg for layers 0/1, ELL one-atomic-pass build.
//
// d_out (N*64 f32) is the final agg buffer.

#define EPS 1e-5f

__device__ __forceinline__ float bf_lo(unsigned u) {
    union { unsigned u; float f; } c; c.u = u << 16; return c.f;
}
__device__ __forceinline__ float bf_hi(unsigned u) {
    union { unsigned u; float f; } c; c.u = u & 0xffff0000u; return c.f;
}
__device__ __forceinline__ unsigned pack_bf2(float a, float b) {
    union { __hip_bfloat16 h; unsigned short u; } ca, cb;
    ca.h = __float2bfloat16(a);
    cb.h = __float2bfloat16(b);
    return (unsigned)ca.u | ((unsigned)cb.u << 16);
}

// ---------------- ELL build ----------------
__global__ __launch_bounds__(256) void k_cursor_init(int* cursor, int CAP, int n) {
    int i = blockIdx.x * 256 + threadIdx.x;
    if (i < n) cursor[i] = i * CAP;
}

__global__ __launch_bounds__(256) void k_fill_ell(const int* __restrict__ src, const int* __restrict__ dst,
                                                  int* cursor, int* __restrict__ ell, int E,
                                                  int lo, int hi) {
    int i = (blockIdx.x * 256 + threadIdx.x) * 4;
    if (i + 3 < E) {
        int4 d = *(const int4*)(dst + i);
        int4 s = *(const int4*)(src + i);
        if (d.x >= lo && d.x < hi) ell[atomicAdd(&cursor[d.x], 1)] = s.x;
        if (d.y >= lo && d.y < hi) ell[atomicAdd(&cursor[d.y], 1)] = s.y;
        if (d.z >= lo && d.z < hi) ell[atomicAdd(&cursor[d.z], 1)] = s.z;
        if (d.w >= lo && d.w < hi) ell[atomicAdd(&cursor[d.w], 1)] = s.w;
    } else {
        for (int t = i; t < E; ++t) {
            int d = dst[t];
            if (d >= lo && d < hi) ell[atomicAdd(&cursor[d], 1)] = src[t];
        }
    }
}

__global__ __launch_bounds__(256) void k_deg_dinv(const int* __restrict__ cursor, float* dinv, int CAP, int n) {
    int i = blockIdx.x * 256 + threadIdx.x;
    if (i < n) dinv[i] = rsqrtf(1.0f + (float)(cursor[i] - i * CAP));
}

// ---------------- fold GraphNorm into weights ----------------
__global__ void k_wprime(const float* __restrict__ W, const float* __restrict__ scale,
                         const float* __restrict__ shift, float* __restrict__ Wp, float* __restrict__ bb) {
    int c = threadIdx.x;  // 64 threads
    float acc = 0.f;
    for (int k = 0; k < 64; ++k) {
        float w = W[k * 64 + c];
        Wp[k * 64 + c] = scale[k] * w;
        acc += shift[k] * w;
    }
    bb[c] = acc;
}

// ---------------- GEMM: out[N][64](bf16) = (in[N][K] @ Wp[K][64] + bb) * dinv[row] ----------------
// BIN=false: in is float[N][K]; BIN=true: in is bf16[N][K].
// W in LDS row-major [k][64]: lane c reads word k*64+c -> bank c%32 (2-way, free).
// x reads are wave-uniform b128 broadcasts (free).
template <int K, bool BIN>
__global__ __launch_bounds__(256) void gemm2(const void* __restrict__ in_, const float* __restrict__ Wp,
                                             const float* __restrict__ bb, const float* __restrict__ dinv,
                                             __hip_bfloat16* __restrict__ out, int N) {
    constexpr int ROWS = 64;
    __shared__ float Wl[K * 64];
    __shared__ float xl[ROWS][K + 4];
    int tid = threadIdx.x;
    int c = tid & 63, rg = tid >> 6;
    int r0 = blockIdx.x * ROWS;

    // stage W: straight contiguous copy (row-major [k][64])
    for (int i = tid; i < K * 16; i += 256) {
        *(float4*)&Wl[i * 4] = *(const float4*)&Wp[i * 4];
    }
    // stage x tile: rows r0..r0+63
    if (!BIN) {
        const float* in = (const float*)in_;
        for (int i = tid; i < ROWS * (K / 4); i += 256) {
            int row = i / (K / 4);
            int kq = (i - row * (K / 4)) << 2;
            int grow = r0 + row;
            float4 v = make_float4(0.f, 0.f, 0.f, 0.f);
            if (grow < N) v = *(const float4*)&in[(size_t)grow * K + kq];
            *(float4*)&xl[row][kq] = v;
        }
    } else {
        const unsigned short* in = (const unsigned short*)in_;
        for (int i = tid; i < ROWS * (K / 8); i += 256) {
            int row = i / (K / 8);
            int k8 = (i - row * (K / 8)) << 3;
            int grow = r0 + row;
            uint4 v = make_uint4(0u, 0u, 0u, 0u);
            if (grow < N) v = *(const uint4*)(in + (size_t)grow * K + k8);
            float4 a = make_float4(bf_lo(v.x), bf_hi(v.x), bf_lo(v.y), bf_hi(v.y));
            float4 bq = make_float4(bf_lo(v.z), bf_hi(v.z), bf_lo(v.w), bf_hi(v.w));
            *(float4*)&xl[row][k8] = a;
            *(float4*)&xl[row][k8 + 4] = bq;
        }
    }
    __syncthreads();

    float acc[16];
#pragma unroll
    for (int j = 0; j < 16; ++j) acc[j] = 0.f;
    for (int k0 = 0; k0 < K; k0 += 4) {
        float w0 = Wl[(k0 + 0) * 64 + c];
        float w1 = Wl[(k0 + 1) * 64 + c];
        float w2 = Wl[(k0 + 2) * 64 + c];
        float w3 = Wl[(k0 + 3) * 64 + c];
#pragma unroll
        for (int j = 0; j < 16; ++j) {
            float4 x4 = *(const float4*)&xl[rg * 16 + j][k0];
            acc[j] = fmaf(x4.x, w0, acc[j]);
            acc[j] = fmaf(x4.y, w1, acc[j]);
            acc[j] = fmaf(x4.z, w2, acc[j]);
            acc[j] = fmaf(x4.w, w3, acc[j]);
        }
    }
    float bbv = bb ? bb[c] : 0.f;
#pragma unroll
    for (int j = 0; j < 16; ++j) {
        int row = r0 + rg * 16 + j;
        if (row < N) out[(size_t)row * 64 + c] = __float2bfloat16((acc[j] + bbv) * dinv[row]);
    }
}

// ---------------- ELL pull: 8-lane group per node, static balanced slots ----------------
// Wave = 8 groups (nodes). Lane cl=lane&7 owns channels [cl*8, cl*8+8).
// Grid sized so each slot handles 3-4 nodes (0.1% imbalance). Full batches of
// 8 edges gather unclamped (8 independent 16B loads in flight), tail clamps.
// OUT_BF16: store agg as bf16 (feeds next gemm2); else fp32 (final layer).
template <bool OUT_BF16>
__global__ __launch_bounds__(256, 4) void k_pull(const int* __restrict__ cursor,
                                                 const int* __restrict__ ell,
                                                 const float* __restrict__ dinv,
                                                 const uint4* __restrict__ xwh,  // 8 x uint4 per row
                                                 const float* __restrict__ bias,
                                                 float* __restrict__ aggf,
                                                 __hip_bfloat16* __restrict__ aggh,
                                                 float* __restrict__ sums, float* __restrict__ sumsq,
                                                 int CAP, int N) {
    int tid = threadIdx.x;
    int lane = tid & 63;
    int g = lane >> 3;   // group (node slot) 0..7
    int cl = lane & 7;   // channel slice
    float bs[8];
#pragma unroll
    for (int k = 0; k < 8; ++k) bs[k] = bias[cl * 8 + k];
    float s_acc[8] = {0, 0, 0, 0, 0, 0, 0, 0};
    float q_acc[8] = {0, 0, 0, 0, 0, 0, 0, 0};

    int slot = (blockIdx.x * 4 + (tid >> 6)) * 8 + g;
    int nslots = gridDim.x * 32;
    for (int n = slot; n < N; n += nslots) {
        int beg = n * CAP, end = cursor[n];
        int last = end - 1;
        float acc[8];
        {   // self row (already scaled by dinv[n])
            uint4 v = xwh[(size_t)n * 8 + cl];
            acc[0] = bf_lo(v.x); acc[1] = bf_hi(v.x);
            acc[2] = bf_lo(v.y); acc[3] = bf_hi(v.y);
            acc[4] = bf_lo(v.z); acc[5] = bf_hi(v.z);
            acc[6] = bf_lo(v.w); acc[7] = bf_hi(v.w);
        }
        int i = beg;
        for (; i + 8 <= end; i += 8) {  // full batches: no clamp/cndmask
            int4 ia = *(const int4*)&ell[i];
            int4 ib = *(const int4*)&ell[i + 4];
            uint4 vv[8];
            vv[0] = xwh[(size_t)ia.x * 8 + cl];
            vv[1] = xwh[(size_t)ia.y * 8 + cl];
            vv[2] = xwh[(size_t)ia.z * 8 + cl];
            vv[3] = xwh[(size_t)ia.w * 8 + cl];
            vv[4] = xwh[(size_t)ib.x * 8 + cl];
            vv[5] = xwh[(size_t)ib.y * 8 + cl];
            vv[6] = xwh[(size_t)ib.z * 8 + cl];
            vv[7] = xwh[(size_t)ib.w * 8 + cl];
#pragma unroll
            for (int k = 0; k < 8; ++k) {
                acc[0] += bf_lo(vv[k].x); acc[1] += bf_hi(vv[k].x);
                acc[2] += bf_lo(vv[k].y); acc[3] += bf_hi(vv[k].y);
                acc[4] += bf_lo(vv[k].z); acc[5] += bf_hi(vv[k].z);
                acc[6] += bf_lo(vv[k].w); acc[7] += bf_hi(vv[k].w);
            }
        }
        if (i < end) {  // tail batch (1..7 edges): clamp + zero
            int4 ia = *(const int4*)&ell[i];
            int4 ib = *(const int4*)&ell[i + 4];
            int ss[8];
            ss[0] = ia.x; ss[1] = ia.y; ss[2] = ia.z; ss[3] = ia.w;
            ss[4] = ib.x; ss[5] = ib.y; ss[6] = ib.z; ss[7] = ib.w;
#pragma unroll
            for (int k = 0; k < 8; ++k) ss[k] = (i + k <= last) ? ss[k] : 0;
            uint4 vv[8];
#pragma unroll
            for (int k = 0; k < 8; ++k) vv[k] = xwh[(size_t)ss[k] * 8 + cl];
#pragma unroll
            for (int k = 0; k < 8; ++k) {
                if (i + k > last) { vv[k].x = 0; vv[k].y = 0; vv[k].z = 0; vv[k].w = 0; }
                acc[0] += bf_lo(vv[k].x); acc[1] += bf_hi(vv[k].x);
                acc[2] += bf_lo(vv[k].y); acc[3] += bf_hi(vv[k].y);
                acc[4] += bf_lo(vv[k].z); acc[5] += bf_hi(vv[k].z);
                acc[6] += bf_lo(vv[k].w); acc[7] += bf_hi(vv[k].w);
            }
        }
        float dn = dinv[n];
        float r[8];
#pragma unroll
        for (int k = 0; k < 8; ++k) {
            r[k] = dn * acc[k] + bs[k];
            s_acc[k] += r[k];
            q_acc[k] += r[k] * r[k];
        }
        if (OUT_BF16) {
            uint4 o;
            o.x = pack_bf2(r[0], r[1]);
            o.y = pack_bf2(r[2], r[3]);
            o.z = pack_bf2(r[4], r[5]);
            o.w = pack_bf2(r[6], r[7]);
            *(uint4*)((unsigned short*)aggh + (size_t)n * 64 + cl * 8) = o;
        } else {
            float4* d4 = (float4*)(aggf + (size_t)n * 64 + cl * 8);
            d4[0] = make_float4(r[0], r[1], r[2], r[3]);
            d4[1] = make_float4(r[4], r[5], r[6], r[7]);
        }
    }

    // block-level stats reduce: stage per-lane partials, 64 threads fold.
    __shared__ float lsum[256][9], lsq[256][9];
#pragma unroll
    for (int k = 0; k < 8; ++k) { lsum[tid][k] = s_acc[k]; lsq[tid][k] = q_acc[k]; }
    __syncthreads();
    if (tid < 64) {
        int cl_t = tid >> 3, k_t = tid & 7;  // channel tid = cl_t*8 + k_t
        float s = 0.f, q = 0.f;
        for (int j = 0; j < 32; ++j) {
            int l = cl_t + 8 * j;
            s += lsum[l][k_t];
            q += lsq[l][k_t];
        }
        atomicAdd(&sums[tid], s);
        atomicAdd(&sumsq[tid], q);
    }
}

// ---------------- GraphNorm params ----------------
__global__ void k_params(const float* __restrict__ sums, const float* __restrict__ sumsq,
                         const float* __restrict__ alpha, const float* __restrict__ gamma,
                         const float* __restrict__ beta, float* scale, float* shift, int N) {
    int c = threadIdx.x;
    float invN = 1.0f / (float)N;
    float m = sums[c] * invN;
    float ex2 = sumsq[c] * invN;
    float a = alpha[c];
    float var = ex2 - 2.0f * a * m * m + a * a * m * m;
    float inv = rsqrtf(var + EPS);
    float sc = gamma[c] * inv;
    scale[c] = sc;
    shift[c] = beta[c] - sc * a * m;
}

__global__ __launch_bounds__(256) void k_final(float* __restrict__ out, const float* __restrict__ scale,
                                               const float* __restrict__ shift, int n64) {
    int i = blockIdx.x * 256 + threadIdx.x;
    if (i < n64) out[i] = scale[i & 63] * out[i] + shift[i & 63];
}

extern "C" void kernel_launch(void* const* d_in, const int* in_sizes, int n_in,
                              void* d_out, int out_size, void* d_ws, size_t ws_size,
                              hipStream_t stream) {
    const float* x     = (const float*)d_in[0];
    const int*   ei    = (const int*)d_in[1];
    const float* W0    = (const float*)d_in[2];
    const float* Wsp   = (const float*)d_in[3];
    const float* b     = (const float*)d_in[4];
    const float* alpha = (const float*)d_in[5];
    const float* gamma = (const float*)d_in[6];
    const float* beta  = (const float*)d_in[7];

    const int N = in_sizes[0] / 128;  // 100000
    const int E = in_sizes[1] / 2;    // 3200000
    const int* src = ei;
    const int* dst = ei + E;

    float* aggf = (float*)d_out;  // N*64 fp32: final-layer agg / output

    const int Na = ((N + 63) / 64) * 64;
    float* ws = (float*)d_ws;
    size_t off = 0;  // in 4-byte units
    float* dinv  = ws + off; off += Na;
    __hip_bfloat16* xwh = (__hip_bfloat16*)(ws + off); off += (size_t)Na * 32;  // N*64 bf16
    __hip_bfloat16* hb  = (__hip_bfloat16*)(ws + off); off += (size_t)Na * 32;  // N*64 bf16 agg (layers 0,1)
    float* sums  = ws + off; off += 64;
    float* sumsq = ws + off; off += 64;
    float* scbuf = ws + off; off += 64;
    float* shbuf = ws + off; off += 64;
    float* Wp    = ws + off; off += 64 * 64;
    float* bbv   = ws + off; off += 64;
    int* cursor  = (int*)(ws + off); off += Na;

    // ELL capacity: Poisson(32) in-degree; P(max deg > 95) ~ 1e-13. Multiple of
    // 8 (int4-aligned batches); +8 pad for int4 tail over-read.
    int CAP = 96;
    while (CAP > 72 && (off + (size_t)N * CAP + 8) * 4 > ws_size) CAP -= 8;
    int* ell = (int*)(ws + off); off += (size_t)N * CAP + 8;

    const int n64 = N * 64;
    const int EB4 = (E / 4 + 255) / 256;
    const int RB = (N + 63) / 64;
    const int NB = (N + 255) / 256;
    // k_pull grid: slots = PB*32; aim for ~4 nodes/slot so max/avg ~= 1.001.
    const int PB = (N + 127) / 128;  // 782 blocks -> 25024 slots, 3-4 nodes each

    // ----- ELL build (reused across 3 layers): ONE atomic pass, no count/scan -----
    k_cursor_init<<<NB, 256, 0, stream>>>(cursor, CAP, N);
    const int NCHUNK = 10;  // write region/chunk ~= 3.84 MB (fits XCD L2)
    int cs = (N + NCHUNK - 1) / NCHUNK;
    for (int c = 0; c < NCHUNK; ++c) {
        int lo = c * cs, hi = min(N, lo + cs);
        k_fill_ell<<<EB4, 256, 0, stream>>>(src, dst, cursor, ell, E, lo, hi);
    }
    k_deg_dinv<<<NB, 256, 0, stream>>>(cursor, dinv, CAP, N);

    // ----- 3 layers -----
    for (int layer = 0; layer < 3; ++layer) {
        if (layer == 0) {
            gemm2<128, false><<<RB, 256, 0, stream>>>(x, W0, nullptr, dinv, xwh, N);
        } else {
            k_wprime<<<1, 64, 0, stream>>>(Wsp + (size_t)(layer - 1) * 64 * 64, scbuf, shbuf, Wp, bbv);
            gemm2<64, true><<<RB, 256, 0, stream>>>(hb, Wp, bbv, dinv, xwh, N);
        }
        hipMemsetAsync(sums, 0, 128 * sizeof(float), stream);  // sums+sumsq contiguous
        if (layer < 2) {
            k_pull<true><<<PB, 256, 0, stream>>>(cursor, ell, dinv, (const uint4*)xwh,
                                                 b + layer * 64, nullptr, hb,
                                                 sums, sumsq, CAP, N);
        } else {
            k_pull<false><<<PB, 256, 0, stream>>>(cursor, ell, dinv, (const uint4*)xwh,
                                                  b + layer * 64, aggf, nullptr,
                                                  sums, sumsq, CAP, N);
        }
        k_params<<<1, 64, 0, stream>>>(sums, sumsq, alpha + layer * 64, gamma + layer * 64,
                                       beta + layer * 64, scbuf, shbuf, N);
    }
    k_final<<<(n64 + 255) / 256, 256, 0, stream>>>(aggf, scbuf, shbuf, n64);
}

// Round 12
// 583.190 us; speedup vs baseline: 1.0399x; 1.0399x over previous
//
#include <hip/hip_runtime.h>
#include <hip/hip_bf16.h>

// GraphStack: 3x (GCNConv -> GraphNorm), N=100000, E=3.2M, D_IN=128, C=64.
//
// Round 12:
//  - gemm2: W read straight from global (L1-hot, 32KB, coalesced 256B/wave)
//    instead of LDS staging. LDS 66.5->33.8 KB (K=128) doubles blocks/CU
//    (round-11 lesson: conflicts were 0 but occupancy 18% -> latency-bound).
//  - Rest identical to round 11: row-major-free gemm x-tile, 8-lane-group
//    k_pull (3-4 nodes/slot), bf16 agg layers 0/1, ELL one-atomic-pass build.
//
// d_out (N*64 f32) is the final agg buffer.

#define EPS 1e-5f

__device__ __forceinline__ float bf_lo(unsigned u) {
    union { unsigned u; float f; } c; c.u = u << 16; return c.f;
}
__device__ __forceinline__ float bf_hi(unsigned u) {
    union { unsigned u; float f; } c; c.u = u & 0xffff0000u; return c.f;
}
__device__ __forceinline__ unsigned pack_bf2(float a, float b) {
    union { __hip_bfloat16 h; unsigned short u; } ca, cb;
    ca.h = __float2bfloat16(a);
    cb.h = __float2bfloat16(b);
    return (unsigned)ca.u | ((unsigned)cb.u << 16);
}

// ---------------- ELL build ----------------
__global__ __launch_bounds__(256) void k_cursor_init(int* cursor, int CAP, int n) {
    int i = blockIdx.x * 256 + threadIdx.x;
    if (i < n) cursor[i] = i * CAP;
}

__global__ __launch_bounds__(256) void k_fill_ell(const int* __restrict__ src, const int* __restrict__ dst,
                                                  int* cursor, int* __restrict__ ell, int E,
                                                  int lo, int hi) {
    int i = (blockIdx.x * 256 + threadIdx.x) * 4;
    if (i + 3 < E) {
        int4 d = *(const int4*)(dst + i);
        int4 s = *(const int4*)(src + i);
        if (d.x >= lo && d.x < hi) ell[atomicAdd(&cursor[d.x], 1)] = s.x;
        if (d.y >= lo && d.y < hi) ell[atomicAdd(&cursor[d.y], 1)] = s.y;
        if (d.z >= lo && d.z < hi) ell[atomicAdd(&cursor[d.z], 1)] = s.z;
        if (d.w >= lo && d.w < hi) ell[atomicAdd(&cursor[d.w], 1)] = s.w;
    } else {
        for (int t = i; t < E; ++t) {
            int d = dst[t];
            if (d >= lo && d < hi) ell[atomicAdd(&cursor[d], 1)] = src[t];
        }
    }
}

__global__ __launch_bounds__(256) void k_deg_dinv(const int* __restrict__ cursor, float* dinv, int CAP, int n) {
    int i = blockIdx.x * 256 + threadIdx.x;
    if (i < n) dinv[i] = rsqrtf(1.0f + (float)(cursor[i] - i * CAP));
}

// ---------------- fold GraphNorm into weights ----------------
__global__ void k_wprime(const float* __restrict__ W, const float* __restrict__ scale,
                         const float* __restrict__ shift, float* __restrict__ Wp, float* __restrict__ bb) {
    int c = threadIdx.x;  // 64 threads
    float acc = 0.f;
    for (int k = 0; k < 64; ++k) {
        float w = W[k * 64 + c];
        Wp[k * 64 + c] = scale[k] * w;
        acc += shift[k] * w;
    }
    bb[c] = acc;
}

// ---------------- GEMM: out[N][64](bf16) = (in[N][K] @ Wp[K][64] + bb) * dinv[row] ----------------
// BIN=false: in is float[N][K]; BIN=true: in is bf16[N][K].
// W read from GLOBAL (L1-hot 32KB, coalesced): no W LDS -> 2x blocks/CU.
// x-tile in LDS, reads are wave-uniform b128 broadcasts (free).
template <int K, bool BIN>
__global__ __launch_bounds__(256) void gemm2(const void* __restrict__ in_, const float* __restrict__ Wp,
                                             const float* __restrict__ bb, const float* __restrict__ dinv,
                                             __hip_bfloat16* __restrict__ out, int N) {
    constexpr int ROWS = 64;
    __shared__ float xl[ROWS][K + 4];
    int tid = threadIdx.x;
    int c = tid & 63, rg = tid >> 6;
    int r0 = blockIdx.x * ROWS;

    // stage x tile: rows r0..r0+63
    if (!BIN) {
        const float* in = (const float*)in_;
        for (int i = tid; i < ROWS * (K / 4); i += 256) {
            int row = i / (K / 4);
            int kq = (i - row * (K / 4)) << 2;
            int grow = r0 + row;
            float4 v = make_float4(0.f, 0.f, 0.f, 0.f);
            if (grow < N) v = *(const float4*)&in[(size_t)grow * K + kq];
            *(float4*)&xl[row][kq] = v;
        }
    } else {
        const unsigned short* in = (const unsigned short*)in_;
        for (int i = tid; i < ROWS * (K / 8); i += 256) {
            int row = i / (K / 8);
            int k8 = (i - row * (K / 8)) << 3;
            int grow = r0 + row;
            uint4 v = make_uint4(0u, 0u, 0u, 0u);
            if (grow < N) v = *(const uint4*)(in + (size_t)grow * K + k8);
            float4 a = make_float4(bf_lo(v.x), bf_hi(v.x), bf_lo(v.y), bf_hi(v.y));
            float4 bq = make_float4(bf_lo(v.z), bf_hi(v.z), bf_lo(v.w), bf_hi(v.w));
            *(float4*)&xl[row][k8] = a;
            *(float4*)&xl[row][k8 + 4] = bq;
        }
    }
    __syncthreads();

    float acc[16];
#pragma unroll
    for (int j = 0; j < 16; ++j) acc[j] = 0.f;
    for (int k0 = 0; k0 < K; k0 += 4) {
        float w0 = Wp[(k0 + 0) * 64 + c];  // global, L1-hot, coalesced
        float w1 = Wp[(k0 + 1) * 64 + c];
        float w2 = Wp[(k0 + 2) * 64 + c];
        float w3 = Wp[(k0 + 3) * 64 + c];
#pragma unroll
        for (int j = 0; j < 16; ++j) {
            float4 x4 = *(const float4*)&xl[rg * 16 + j][k0];
            acc[j] = fmaf(x4.x, w0, acc[j]);
            acc[j] = fmaf(x4.y, w1, acc[j]);
            acc[j] = fmaf(x4.z, w2, acc[j]);
            acc[j] = fmaf(x4.w, w3, acc[j]);
        }
    }
    float bbv = bb ? bb[c] : 0.f;
#pragma unroll
    for (int j = 0; j < 16; ++j) {
        int row = r0 + rg * 16 + j;
        if (row < N) out[(size_t)row * 64 + c] = __float2bfloat16((acc[j] + bbv) * dinv[row]);
    }
}

// ---------------- ELL pull: 8-lane group per node, static balanced slots ----------------
// Wave = 8 groups (nodes). Lane cl=lane&7 owns channels [cl*8, cl*8+8).
// Grid sized so each slot handles 3-4 nodes (0.1% imbalance). Full batches of
// 8 edges gather unclamped (8 independent 16B loads in flight), tail clamps.
// OUT_BF16: store agg as bf16 (feeds next gemm2); else fp32 (final layer).
template <bool OUT_BF16>
__global__ __launch_bounds__(256, 4) void k_pull(const int* __restrict__ cursor,
                                                 const int* __restrict__ ell,
                                                 const float* __restrict__ dinv,
                                                 const uint4* __restrict__ xwh,  // 8 x uint4 per row
                                                 const float* __restrict__ bias,
                                                 float* __restrict__ aggf,
                                                 __hip_bfloat16* __restrict__ aggh,
                                                 float* __restrict__ sums, float* __restrict__ sumsq,
                                                 int CAP, int N) {
    int tid = threadIdx.x;
    int lane = tid & 63;
    int g = lane >> 3;   // group (node slot) 0..7
    int cl = lane & 7;   // channel slice
    float bs[8];
#pragma unroll
    for (int k = 0; k < 8; ++k) bs[k] = bias[cl * 8 + k];
    float s_acc[8] = {0, 0, 0, 0, 0, 0, 0, 0};
    float q_acc[8] = {0, 0, 0, 0, 0, 0, 0, 0};

    int slot = (blockIdx.x * 4 + (tid >> 6)) * 8 + g;
    int nslots = gridDim.x * 32;
    for (int n = slot; n < N; n += nslots) {
        int beg = n * CAP, end = cursor[n];
        int last = end - 1;
        float acc[8];
        {   // self row (already scaled by dinv[n])
            uint4 v = xwh[(size_t)n * 8 + cl];
            acc[0] = bf_lo(v.x); acc[1] = bf_hi(v.x);
            acc[2] = bf_lo(v.y); acc[3] = bf_hi(v.y);
            acc[4] = bf_lo(v.z); acc[5] = bf_hi(v.z);
            acc[6] = bf_lo(v.w); acc[7] = bf_hi(v.w);
        }
        int i = beg;
        for (; i + 8 <= end; i += 8) {  // full batches: no clamp/cndmask
            int4 ia = *(const int4*)&ell[i];
            int4 ib = *(const int4*)&ell[i + 4];
            uint4 vv[8];
            vv[0] = xwh[(size_t)ia.x * 8 + cl];
            vv[1] = xwh[(size_t)ia.y * 8 + cl];
            vv[2] = xwh[(size_t)ia.z * 8 + cl];
            vv[3] = xwh[(size_t)ia.w * 8 + cl];
            vv[4] = xwh[(size_t)ib.x * 8 + cl];
            vv[5] = xwh[(size_t)ib.y * 8 + cl];
            vv[6] = xwh[(size_t)ib.z * 8 + cl];
            vv[7] = xwh[(size_t)ib.w * 8 + cl];
#pragma unroll
            for (int k = 0; k < 8; ++k) {
                acc[0] += bf_lo(vv[k].x); acc[1] += bf_hi(vv[k].x);
                acc[2] += bf_lo(vv[k].y); acc[3] += bf_hi(vv[k].y);
                acc[4] += bf_lo(vv[k].z); acc[5] += bf_hi(vv[k].z);
                acc[6] += bf_lo(vv[k].w); acc[7] += bf_hi(vv[k].w);
            }
        }
        if (i < end) {  // tail batch (1..7 edges): clamp + zero
            int4 ia = *(const int4*)&ell[i];
            int4 ib = *(const int4*)&ell[i + 4];
            int ss[8];
            ss[0] = ia.x; ss[1] = ia.y; ss[2] = ia.z; ss[3] = ia.w;
            ss[4] = ib.x; ss[5] = ib.y; ss[6] = ib.z; ss[7] = ib.w;
#pragma unroll
            for (int k = 0; k < 8; ++k) ss[k] = (i + k <= last) ? ss[k] : 0;
            uint4 vv[8];
#pragma unroll
            for (int k = 0; k < 8; ++k) vv[k] = xwh[(size_t)ss[k] * 8 + cl];
#pragma unroll
            for (int k = 0; k < 8; ++k) {
                if (i + k > last) { vv[k].x = 0; vv[k].y = 0; vv[k].z = 0; vv[k].w = 0; }
                acc[0] += bf_lo(vv[k].x); acc[1] += bf_hi(vv[k].x);
                acc[2] += bf_lo(vv[k].y); acc[3] += bf_hi(vv[k].y);
                acc[4] += bf_lo(vv[k].z); acc[5] += bf_hi(vv[k].z);
                acc[6] += bf_lo(vv[k].w); acc[7] += bf_hi(vv[k].w);
            }
        }
        float dn = dinv[n];
        float r[8];
#pragma unroll
        for (int k = 0; k < 8; ++k) {
            r[k] = dn * acc[k] + bs[k];
            s_acc[k] += r[k];
            q_acc[k] += r[k] * r[k];
        }
        if (OUT_BF16) {
            uint4 o;
            o.x = pack_bf2(r[0], r[1]);
            o.y = pack_bf2(r[2], r[3]);
            o.z = pack_bf2(r[4], r[5]);
            o.w = pack_bf2(r[6], r[7]);
            *(uint4*)((unsigned short*)aggh + (size_t)n * 64 + cl * 8) = o;
        } else {
            float4* d4 = (float4*)(aggf + (size_t)n * 64 + cl * 8);
            d4[0] = make_float4(r[0], r[1], r[2], r[3]);
            d4[1] = make_float4(r[4], r[5], r[6], r[7]);
        }
    }

    // block-level stats reduce: stage per-lane partials, 64 threads fold.
    __shared__ float lsum[256][9], lsq[256][9];
#pragma unroll
    for (int k = 0; k < 8; ++k) { lsum[tid][k] = s_acc[k]; lsq[tid][k] = q_acc[k]; }
    __syncthreads();
    if (tid < 64) {
        int cl_t = tid >> 3, k_t = tid & 7;  // channel tid = cl_t*8 + k_t
        float s = 0.f, q = 0.f;
        for (int j = 0; j < 32; ++j) {
            int l = cl_t + 8 * j;
            s += lsum[l][k_t];
            q += lsq[l][k_t];
        }
        atomicAdd(&sums[tid], s);
        atomicAdd(&sumsq[tid], q);
    }
}

// ---------------- GraphNorm params ----------------
__global__ void k_params(const float* __restrict__ sums, const float* __restrict__ sumsq,
                         const float* __restrict__ alpha, const float* __restrict__ gamma,
                         const float* __restrict__ beta, float* scale, float* shift, int N) {
    int c = threadIdx.x;
    float invN = 1.0f / (float)N;
    float m = sums[c] * invN;
    float ex2 = sumsq[c] * invN;
    float a = alpha[c];
    float var = ex2 - 2.0f * a * m * m + a * a * m * m;
    float inv = rsqrtf(var + EPS);
    float sc = gamma[c] * inv;
    scale[c] = sc;
    shift[c] = beta[c] - sc * a * m;
}

__global__ __launch_bounds__(256) void k_final(float* __restrict__ out, const float* __restrict__ scale,
                                               const float* __restrict__ shift, int n64) {
    int i = blockIdx.x * 256 + threadIdx.x;
    if (i < n64) out[i] = scale[i & 63] * out[i] + shift[i & 63];
}

extern "C" void kernel_launch(void* const* d_in, const int* in_sizes, int n_in,
                              void* d_out, int out_size, void* d_ws, size_t ws_size,
                              hipStream_t stream) {
    const float* x     = (const float*)d_in[0];
    const int*   ei    = (const int*)d_in[1];
    const float* W0    = (const float*)d_in[2];
    const float* Wsp   = (const float*)d_in[3];
    const float* b     = (const float*)d_in[4];
    const float* alpha = (const float*)d_in[5];
    const float* gamma = (const float*)d_in[6];
    const float* beta  = (const float*)d_in[7];

    const int N = in_sizes[0] / 128;  // 100000
    const int E = in_sizes[1] / 2;    // 3200000
    const int* src = ei;
    const int* dst = ei + E;

    float* aggf = (float*)d_out;  // N*64 fp32: final-layer agg / output

    const int Na = ((N + 63) / 64) * 64;
    float* ws = (float*)d_ws;
    size_t off = 0;  // in 4-byte units
    float* dinv  = ws + off; off += Na;
    __hip_bfloat16* xwh = (__hip_bfloat16*)(ws + off); off += (size_t)Na * 32;  // N*64 bf16
    __hip_bfloat16* hb  = (__hip_bfloat16*)(ws + off); off += (size_t)Na * 32;  // N*64 bf16 agg (layers 0,1)
    float* sums  = ws + off; off += 64;
    float* sumsq = ws + off; off += 64;
    float* scbuf = ws + off; off += 64;
    float* shbuf = ws + off; off += 64;
    float* Wp    = ws + off; off += 64 * 64;
    float* bbv   = ws + off; off += 64;
    int* cursor  = (int*)(ws + off); off += Na;

    // ELL capacity: Poisson(32) in-degree; P(max deg > 95) ~ 1e-13. Multiple of
    // 8 (int4-aligned batches); +8 pad for int4 tail over-read.
    int CAP = 96;
    while (CAP > 72 && (off + (size_t)N * CAP + 8) * 4 > ws_size) CAP -= 8;
    int* ell = (int*)(ws + off); off += (size_t)N * CAP + 8;

    const int n64 = N * 64;
    const int EB4 = (E / 4 + 255) / 256;
    const int RB = (N + 63) / 64;
    const int NB = (N + 255) / 256;
    // k_pull grid: slots = PB*32; aim for ~4 nodes/slot so max/avg ~= 1.001.
    const int PB = (N + 127) / 128;  // 782 blocks -> 25024 slots, 3-4 nodes each

    // ----- ELL build (reused across 3 layers): ONE atomic pass, no count/scan -----
    k_cursor_init<<<NB, 256, 0, stream>>>(cursor, CAP, N);
    const int NCHUNK = 10;  // write region/chunk ~= 3.84 MB (fits XCD L2)
    int cs = (N + NCHUNK - 1) / NCHUNK;
    for (int c = 0; c < NCHUNK; ++c) {
        int lo = c * cs, hi = min(N, lo + cs);
        k_fill_ell<<<EB4, 256, 0, stream>>>(src, dst, cursor, ell, E, lo, hi);
    }
    k_deg_dinv<<<NB, 256, 0, stream>>>(cursor, dinv, CAP, N);

    // ----- 3 layers -----
    for (int layer = 0; layer < 3; ++layer) {
        if (layer == 0) {
            gemm2<128, false><<<RB, 256, 0, stream>>>(x, W0, nullptr, dinv, xwh, N);
        } else {
            k_wprime<<<1, 64, 0, stream>>>(Wsp + (size_t)(layer - 1) * 64 * 64, scbuf, shbuf, Wp, bbv);
            gemm2<64, true><<<RB, 256, 0, stream>>>(hb, Wp, bbv, dinv, xwh, N);
        }
        hipMemsetAsync(sums, 0, 128 * sizeof(float), stream);  // sums+sumsq contiguous
        if (layer < 2) {
            k_pull<true><<<PB, 256, 0, stream>>>(cursor, ell, dinv, (const uint4*)xwh,
                                                 b + layer * 64, nullptr, hb,
                                                 sums, sumsq, CAP, N);
        } else {
            k_pull<false><<<PB, 256, 0, stream>>>(cursor, ell, dinv, (const uint4*)xwh,
                                                  b + layer * 64, aggf, nullptr,
                                                  sums, sumsq, CAP, N);
        }
        k_params<<<1, 64, 0, stream>>>(sums, sumsq, alpha + layer * 64, gamma + layer * 64,
                                       beta + layer * 64, scbuf, shbuf, N);
    }
    k_final<<<(n64 + 255) / 256, 256, 0, stream>>>(aggf, scbuf, shbuf, n64);
}

// Round 13
// 423.233 us; speedup vs baseline: 1.4329x; 1.3779x over previous
//
#include <hip/hip_runtime.h>
#include <hip/hip_bf16.h>

// GraphStack: 3x (GCNConv -> GraphNorm), N=100000, E=3.2M, D_IN=128, C=64.
//
// Round 13:
//  - ELL build rewritten as scan-based radix partition (NO global atomics):
//    hist(LDS) -> 2-level scan -> scatter(LDS cursors) -> per-bucket ELL fill
//    with LDS atomics + coalesced writeback. Scratch overlays xwh/hb (dead
//    during build) -> zero extra workspace. Old atomic path kept as fallback.
//  - k_pull grid 782->1563 blocks (2 nodes/slot exact): occupancy 24->~45%.
//  - Rest as round 12 (W-from-global gemm2, bf16 agg layers 0/1).
//
// d_out (N*64 f32) is the final agg buffer.

#define EPS 1e-5f

__device__ __forceinline__ float bf_lo(unsigned u) {
    union { unsigned u; float f; } c; c.u = u << 16; return c.f;
}
__device__ __forceinline__ float bf_hi(unsigned u) {
    union { unsigned u; float f; } c; c.u = u & 0xffff0000u; return c.f;
}
__device__ __forceinline__ unsigned pack_bf2(float a, float b) {
    union { __hip_bfloat16 h; unsigned short u; } ca, cb;
    ca.h = __float2bfloat16(a);
    cb.h = __float2bfloat16(b);
    return (unsigned)ca.u | ((unsigned)cb.u << 16);
}

// ================= scan-based ELL build (fast path) =================
// Buckets: 64 nodes each, bkt = dst>>6. Segments: NSEG=256 blocks over edges.

__global__ __launch_bounds__(256) void k_hist(const int* __restrict__ dst, int* __restrict__ hist,
                                              int E, int SEG, int NBKT) {
    __shared__ int h[2048];
    int t = threadIdx.x;
    for (int b = t; b < NBKT; b += 256) h[b] = 0;
    __syncthreads();
    int i0 = blockIdx.x * SEG, i1 = min(E, i0 + SEG);
    for (int i = i0 + t * 4; i < i1; i += 1024) {
        if (i + 3 < i1) {
            int4 d = *(const int4*)(dst + i);
            atomicAdd(&h[d.x >> 6], 1);
            atomicAdd(&h[d.y >> 6], 1);
            atomicAdd(&h[d.z >> 6], 1);
            atomicAdd(&h[d.w >> 6], 1);
        } else {
            for (int q = i; q < i1; ++q) atomicAdd(&h[dst[q] >> 6], 1);
        }
    }
    __syncthreads();
    for (int b = t; b < NBKT; b += 256) hist[blockIdx.x * NBKT + b] = h[b];
}

// Exclusive scan of hist in bucket-major logical order (l = bkt*256 + blk).
// Chunk = 1024 logical elements per block; writes per-element exclusive scan
// (within chunk) + chunk totals.
__global__ __launch_bounds__(256) void k_scanA(const int* __restrict__ hist, int* __restrict__ chunkScan,
                                               int* __restrict__ chunkTot, int NBKT, int SCAN_N) {
    __shared__ int ls[256];
    int t = threadIdx.x;
    int base = blockIdx.x * 1024 + t * 4;
    int v[4];
#pragma unroll
    for (int j = 0; j < 4; ++j) {
        int l = base + j;
        v[j] = 0;
        if (l < SCAN_N) {
            int blk = l & 255, bkt = l >> 8;
            v[j] = hist[blk * NBKT + bkt];
        }
    }
    int s = v[0] + v[1] + v[2] + v[3];
    ls[t] = s;
    __syncthreads();
    for (int off = 1; off < 256; off <<= 1) {
        int val = (t >= off) ? ls[t - off] : 0;
        __syncthreads();
        ls[t] += val;
        __syncthreads();
    }
    int run = ls[t] - s;  // exclusive base for this thread within chunk
#pragma unroll
    for (int j = 0; j < 4; ++j) {
        chunkScan[base + j] = run;
        run += v[j];
    }
    if (t == 255) chunkTot[blockIdx.x] = ls[255];
}

// Single-block inclusive scan of up to 512 chunk totals -> exclusive bases.
__global__ void k_scanB(const int* __restrict__ chunkTot, int* __restrict__ chunkBase, int NCH) {
    __shared__ int s[512];
    int t = threadIdx.x;  // 256 threads
    s[t] = (t < NCH) ? chunkTot[t] : 0;
    s[t + 256] = (t + 256 < NCH) ? chunkTot[t + 256] : 0;
    __syncthreads();
    for (int off = 1; off < 512; off <<= 1) {
        int a0 = (t >= off) ? s[t - off] : 0;
        int a1 = (t + 256 >= off) ? s[t + 256 - off] : 0;
        __syncthreads();
        s[t] += a0;
        s[t + 256] += a1;
        __syncthreads();
    }
    if (t < NCH) chunkBase[t] = t ? s[t - 1] : 0;
    if (t + 256 < NCH) chunkBase[t + 256] = s[t + 255];
}

// Scatter edges into bucket-partitioned packed array: val = src | (dst&63)<<26.
__global__ __launch_bounds__(256) void k_scatter_part(const int* __restrict__ src, const int* __restrict__ dst,
                                                      const int* __restrict__ chunkScan,
                                                      const int* __restrict__ chunkBase,
                                                      int* __restrict__ packed, int E, int SEG, int NBKT) {
    __shared__ int cur[2048];
    int blk = blockIdx.x, t = threadIdx.x;
    for (int b = t; b < NBKT; b += 256) {
        int l = b * 256 + blk;
        cur[b] = chunkScan[l] + chunkBase[l >> 10];
    }
    __syncthreads();
    int i0 = blk * SEG, i1 = min(E, i0 + SEG);
    for (int i = i0 + t * 4; i < i1; i += 1024) {
        if (i + 3 < i1) {
            int4 d = *(const int4*)(dst + i);
            int4 s = *(const int4*)(src + i);
            int p;
            p = atomicAdd(&cur[d.x >> 6], 1); packed[p] = (int)(((unsigned)(d.x & 63) << 26) | (unsigned)s.x);
            p = atomicAdd(&cur[d.y >> 6], 1); packed[p] = (int)(((unsigned)(d.y & 63) << 26) | (unsigned)s.y);
            p = atomicAdd(&cur[d.z >> 6], 1); packed[p] = (int)(((unsigned)(d.z & 63) << 26) | (unsigned)s.z);
            p = atomicAdd(&cur[d.w >> 6], 1); packed[p] = (int)(((unsigned)(d.w & 63) << 26) | (unsigned)s.w);
        } else {
            for (int q = i; q < i1; ++q) {
                int dd = dst[q];
                int p = atomicAdd(&cur[dd >> 6], 1);
                packed[p] = (int)(((unsigned)(dd & 63) << 26) | (unsigned)src[q]);
            }
        }
    }
}

// One block per bucket: build 64-node ELL slice in LDS, write back coalesced.
__global__ __launch_bounds__(256) void k_ellfill(const int* __restrict__ packed,
                                                 const int* __restrict__ chunkScan,
                                                 const int* __restrict__ chunkBase,
                                                 int* __restrict__ ell, int* __restrict__ cursor,
                                                 float* __restrict__ dinv,
                                                 int CAP, int NBKT, int N, int E) {
    __shared__ int ellLoc[64 * 96];
    __shared__ int cnt[64];
    int bkt = blockIdx.x, t = threadIdx.x;
    if (t < 64) cnt[t] = 0;
    __syncthreads();
    int l0 = bkt * 256;
    int bs = chunkScan[l0] + chunkBase[l0 >> 10];
    int be = E;
    if (bkt + 1 < NBKT) {
        int l1 = (bkt + 1) * 256;
        be = chunkScan[l1] + chunkBase[l1 >> 10];
    }
    for (int i = bs + t; i < be; i += 256) {
        unsigned p = (unsigned)packed[i];
        int s = (int)(p & 0x03FFFFFFu);
        int ld = (int)(p >> 26);
        int slot = atomicAdd(&cnt[ld], 1);
        if (slot < CAP) ellLoc[ld * CAP + slot] = s;
    }
    __syncthreads();
    int lo = bkt << 6;
    int total = 64 * CAP;
    for (int idx = t; idx < total; idx += 256) {
        int ld = idx / CAP;
        int s = idx - ld * CAP;
        if (lo + ld < N && s < min(cnt[ld], CAP))
            ell[(size_t)lo * CAP + idx] = ellLoc[idx];
    }
    if (t < 64 && lo + t < N) {
        int dg = min(cnt[t], CAP);
        cursor[lo + t] = (lo + t) * CAP + dg;
        dinv[lo + t] = rsqrtf(1.0f + (float)cnt[t]);
    }
}

// ================= fallback ELL build (atomic path, round 12) =================
__global__ __launch_bounds__(256) void k_cursor_init(int* cursor, int CAP, int n) {
    int i = blockIdx.x * 256 + threadIdx.x;
    if (i < n) cursor[i] = i * CAP;
}

__global__ __launch_bounds__(256) void k_fill_ell(const int* __restrict__ src, const int* __restrict__ dst,
                                                  int* cursor, int* __restrict__ ell, int E,
                                                  int lo, int hi) {
    int i = (blockIdx.x * 256 + threadIdx.x) * 4;
    if (i + 3 < E) {
        int4 d = *(const int4*)(dst + i);
        int4 s = *(const int4*)(src + i);
        if (d.x >= lo && d.x < hi) ell[atomicAdd(&cursor[d.x], 1)] = s.x;
        if (d.y >= lo && d.y < hi) ell[atomicAdd(&cursor[d.y], 1)] = s.y;
        if (d.z >= lo && d.z < hi) ell[atomicAdd(&cursor[d.z], 1)] = s.z;
        if (d.w >= lo && d.w < hi) ell[atomicAdd(&cursor[d.w], 1)] = s.w;
    } else {
        for (int t = i; t < E; ++t) {
            int d = dst[t];
            if (d >= lo && d < hi) ell[atomicAdd(&cursor[d], 1)] = src[t];
        }
    }
}

__global__ __launch_bounds__(256) void k_deg_dinv(const int* __restrict__ cursor, float* dinv, int CAP, int n) {
    int i = blockIdx.x * 256 + threadIdx.x;
    if (i < n) dinv[i] = rsqrtf(1.0f + (float)(cursor[i] - i * CAP));
}

// ---------------- fold GraphNorm into weights ----------------
__global__ void k_wprime(const float* __restrict__ W, const float* __restrict__ scale,
                         const float* __restrict__ shift, float* __restrict__ Wp, float* __restrict__ bb) {
    int c = threadIdx.x;  // 64 threads
    float acc = 0.f;
    for (int k = 0; k < 64; ++k) {
        float w = W[k * 64 + c];
        Wp[k * 64 + c] = scale[k] * w;
        acc += shift[k] * w;
    }
    bb[c] = acc;
}

// ---------------- GEMM: out[N][64](bf16) = (in[N][K] @ Wp[K][64] + bb) * dinv[row] ----------------
template <int K, bool BIN>
__global__ __launch_bounds__(256) void gemm2(const void* __restrict__ in_, const float* __restrict__ Wp,
                                             const float* __restrict__ bb, const float* __restrict__ dinv,
                                             __hip_bfloat16* __restrict__ out, int N) {
    constexpr int ROWS = 64;
    __shared__ float xl[ROWS][K + 4];
    int tid = threadIdx.x;
    int c = tid & 63, rg = tid >> 6;
    int r0 = blockIdx.x * ROWS;

    if (!BIN) {
        const float* in = (const float*)in_;
        for (int i = tid; i < ROWS * (K / 4); i += 256) {
            int row = i / (K / 4);
            int kq = (i - row * (K / 4)) << 2;
            int grow = r0 + row;
            float4 v = make_float4(0.f, 0.f, 0.f, 0.f);
            if (grow < N) v = *(const float4*)&in[(size_t)grow * K + kq];
            *(float4*)&xl[row][kq] = v;
        }
    } else {
        const unsigned short* in = (const unsigned short*)in_;
        for (int i = tid; i < ROWS * (K / 8); i += 256) {
            int row = i / (K / 8);
            int k8 = (i - row * (K / 8)) << 3;
            int grow = r0 + row;
            uint4 v = make_uint4(0u, 0u, 0u, 0u);
            if (grow < N) v = *(const uint4*)(in + (size_t)grow * K + k8);
            float4 a = make_float4(bf_lo(v.x), bf_hi(v.x), bf_lo(v.y), bf_hi(v.y));
            float4 bq = make_float4(bf_lo(v.z), bf_hi(v.z), bf_lo(v.w), bf_hi(v.w));
            *(float4*)&xl[row][k8] = a;
            *(float4*)&xl[row][k8 + 4] = bq;
        }
    }
    __syncthreads();

    float acc[16];
#pragma unroll
    for (int j = 0; j < 16; ++j) acc[j] = 0.f;
    for (int k0 = 0; k0 < K; k0 += 4) {
        float w0 = Wp[(k0 + 0) * 64 + c];  // global, L1-hot, coalesced
        float w1 = Wp[(k0 + 1) * 64 + c];
        float w2 = Wp[(k0 + 2) * 64 + c];
        float w3 = Wp[(k0 + 3) * 64 + c];
#pragma unroll
        for (int j = 0; j < 16; ++j) {
            float4 x4 = *(const float4*)&xl[rg * 16 + j][k0];
            acc[j] = fmaf(x4.x, w0, acc[j]);
            acc[j] = fmaf(x4.y, w1, acc[j]);
            acc[j] = fmaf(x4.z, w2, acc[j]);
            acc[j] = fmaf(x4.w, w3, acc[j]);
        }
    }
    float bbv = bb ? bb[c] : 0.f;
#pragma unroll
    for (int j = 0; j < 16; ++j) {
        int row = r0 + rg * 16 + j;
        if (row < N) out[(size_t)row * 64 + c] = __float2bfloat16((acc[j] + bbv) * dinv[row]);
    }
}

// ---------------- ELL pull: 8-lane group per node, static balanced slots ----------------
template <bool OUT_BF16>
__global__ __launch_bounds__(256, 4) void k_pull(const int* __restrict__ cursor,
                                                 const int* __restrict__ ell,
                                                 const float* __restrict__ dinv,
                                                 const uint4* __restrict__ xwh,  // 8 x uint4 per row
                                                 const float* __restrict__ bias,
                                                 float* __restrict__ aggf,
                                                 __hip_bfloat16* __restrict__ aggh,
                                                 float* __restrict__ sums, float* __restrict__ sumsq,
                                                 int CAP, int N) {
    int tid = threadIdx.x;
    int lane = tid & 63;
    int g = lane >> 3;   // group (node slot) 0..7
    int cl = lane & 7;   // channel slice
    float bs[8];
#pragma unroll
    for (int k = 0; k < 8; ++k) bs[k] = bias[cl * 8 + k];
    float s_acc[8] = {0, 0, 0, 0, 0, 0, 0, 0};
    float q_acc[8] = {0, 0, 0, 0, 0, 0, 0, 0};

    int slot = (blockIdx.x * 4 + (tid >> 6)) * 8 + g;
    int nslots = gridDim.x * 32;
    for (int n = slot; n < N; n += nslots) {
        int beg = n * CAP, end = cursor[n];
        int last = end - 1;
        float acc[8];
        {   // self row (already scaled by dinv[n])
            uint4 v = xwh[(size_t)n * 8 + cl];
            acc[0] = bf_lo(v.x); acc[1] = bf_hi(v.x);
            acc[2] = bf_lo(v.y); acc[3] = bf_hi(v.y);
            acc[4] = bf_lo(v.z); acc[5] = bf_hi(v.z);
            acc[6] = bf_lo(v.w); acc[7] = bf_hi(v.w);
        }
        int i = beg;
        for (; i + 8 <= end; i += 8) {  // full batches: no clamp/cndmask
            int4 ia = *(const int4*)&ell[i];
            int4 ib = *(const int4*)&ell[i + 4];
            uint4 vv[8];
            vv[0] = xwh[(size_t)ia.x * 8 + cl];
            vv[1] = xwh[(size_t)ia.y * 8 + cl];
            vv[2] = xwh[(size_t)ia.z * 8 + cl];
            vv[3] = xwh[(size_t)ia.w * 8 + cl];
            vv[4] = xwh[(size_t)ib.x * 8 + cl];
            vv[5] = xwh[(size_t)ib.y * 8 + cl];
            vv[6] = xwh[(size_t)ib.z * 8 + cl];
            vv[7] = xwh[(size_t)ib.w * 8 + cl];
#pragma unroll
            for (int k = 0; k < 8; ++k) {
                acc[0] += bf_lo(vv[k].x); acc[1] += bf_hi(vv[k].x);
                acc[2] += bf_lo(vv[k].y); acc[3] += bf_hi(vv[k].y);
                acc[4] += bf_lo(vv[k].z); acc[5] += bf_hi(vv[k].z);
                acc[6] += bf_lo(vv[k].w); acc[7] += bf_hi(vv[k].w);
            }
        }
        if (i < end) {  // tail batch (1..7 edges): clamp + zero
            int4 ia = *(const int4*)&ell[i];
            int4 ib = *(const int4*)&ell[i + 4];
            int ss[8];
            ss[0] = ia.x; ss[1] = ia.y; ss[2] = ia.z; ss[3] = ia.w;
            ss[4] = ib.x; ss[5] = ib.y; ss[6] = ib.z; ss[7] = ib.w;
#pragma unroll
            for (int k = 0; k < 8; ++k) ss[k] = (i + k <= last) ? ss[k] : 0;
            uint4 vv[8];
#pragma unroll
            for (int k = 0; k < 8; ++k) vv[k] = xwh[(size_t)ss[k] * 8 + cl];
#pragma unroll
            for (int k = 0; k < 8; ++k) {
                if (i + k > last) { vv[k].x = 0; vv[k].y = 0; vv[k].z = 0; vv[k].w = 0; }
                acc[0] += bf_lo(vv[k].x); acc[1] += bf_hi(vv[k].x);
                acc[2] += bf_lo(vv[k].y); acc[3] += bf_hi(vv[k].y);
                acc[4] += bf_lo(vv[k].z); acc[5] += bf_hi(vv[k].z);
                acc[6] += bf_lo(vv[k].w); acc[7] += bf_hi(vv[k].w);
            }
        }
        float dn = dinv[n];
        float r[8];
#pragma unroll
        for (int k = 0; k < 8; ++k) {
            r[k] = dn * acc[k] + bs[k];
            s_acc[k] += r[k];
            q_acc[k] += r[k] * r[k];
        }
        if (OUT_BF16) {
            uint4 o;
            o.x = pack_bf2(r[0], r[1]);
            o.y = pack_bf2(r[2], r[3]);
            o.z = pack_bf2(r[4], r[5]);
            o.w = pack_bf2(r[6], r[7]);
            *(uint4*)((unsigned short*)aggh + (size_t)n * 64 + cl * 8) = o;
        } else {
            float4* d4 = (float4*)(aggf + (size_t)n * 64 + cl * 8);
            d4[0] = make_float4(r[0], r[1], r[2], r[3]);
            d4[1] = make_float4(r[4], r[5], r[6], r[7]);
        }
    }

    // block-level stats reduce: stage per-lane partials, 64 threads fold.
    __shared__ float lsum[256][9], lsq[256][9];
#pragma unroll
    for (int k = 0; k < 8; ++k) { lsum[tid][k] = s_acc[k]; lsq[tid][k] = q_acc[k]; }
    __syncthreads();
    if (tid < 64) {
        int cl_t = tid >> 3, k_t = tid & 7;  // channel tid = cl_t*8 + k_t
        float s = 0.f, q = 0.f;
        for (int j = 0; j < 32; ++j) {
            int l = cl_t + 8 * j;
            s += lsum[l][k_t];
            q += lsq[l][k_t];
        }
        atomicAdd(&sums[tid], s);
        atomicAdd(&sumsq[tid], q);
    }
}

// ---------------- GraphNorm params ----------------
__global__ void k_params(const float* __restrict__ sums, const float* __restrict__ sumsq,
                         const float* __restrict__ alpha, const float* __restrict__ gamma,
                         const float* __restrict__ beta, float* scale, float* shift, int N) {
    int c = threadIdx.x;
    float invN = 1.0f / (float)N;
    float m = sums[c] * invN;
    float ex2 = sumsq[c] * invN;
    float a = alpha[c];
    float var = ex2 - 2.0f * a * m * m + a * a * m * m;
    float inv = rsqrtf(var + EPS);
    float sc = gamma[c] * inv;
    scale[c] = sc;
    shift[c] = beta[c] - sc * a * m;
}

__global__ __launch_bounds__(256) void k_final(float* __restrict__ out, const float* __restrict__ scale,
                                               const float* __restrict__ shift, int n64) {
    int i = blockIdx.x * 256 + threadIdx.x;
    if (i < n64) out[i] = scale[i & 63] * out[i] + shift[i & 63];
}

extern "C" void kernel_launch(void* const* d_in, const int* in_sizes, int n_in,
                              void* d_out, int out_size, void* d_ws, size_t ws_size,
                              hipStream_t stream) {
    const float* x     = (const float*)d_in[0];
    const int*   ei    = (const int*)d_in[1];
    const float* W0    = (const float*)d_in[2];
    const float* Wsp   = (const float*)d_in[3];
    const float* b     = (const float*)d_in[4];
    const float* alpha = (const float*)d_in[5];
    const float* gamma = (const float*)d_in[6];
    const float* beta  = (const float*)d_in[7];

    const int N = in_sizes[0] / 128;  // 100000
    const int E = in_sizes[1] / 2;    // 3200000
    const int* src = ei;
    const int* dst = ei + E;

    float* aggf = (float*)d_out;  // N*64 fp32: final-layer agg / output

    const int Na = ((N + 63) / 64) * 64;
    float* ws = (float*)d_ws;
    size_t off = 0;  // in 4-byte units
    float* dinv  = ws + off; off += Na;
    __hip_bfloat16* xwh = (__hip_bfloat16*)(ws + off); off += (size_t)Na * 32;  // N*64 bf16
    __hip_bfloat16* hb  = (__hip_bfloat16*)(ws + off); off += (size_t)Na * 32;  // N*64 bf16 agg (layers 0,1)
    float* sums  = ws + off; off += 64;
    float* sumsq = ws + off; off += 64;
    float* scbuf = ws + off; off += 64;
    float* shbuf = ws + off; off += 64;
    float* Wp    = ws + off; off += 64 * 64;
    float* bbv   = ws + off; off += 64;
    int* cursor  = (int*)(ws + off); off += Na;

    // ELL capacity: Poisson(32) in-degree; P(max deg > 95) ~ 1e-13. Multiple of
    // 8 (int4-aligned batches); +8 pad for int4 tail over-read.
    int CAP = 96;
    while (CAP > 72 && (off + (size_t)N * CAP + 8) * 4 > ws_size) CAP -= 8;
    int* ell = (int*)(ws + off); off += (size_t)N * CAP + 8;

    const int n64 = N * 64;
    const int RB = (N + 63) / 64;
    const int NB = (N + 255) / 256;
    // k_pull grid: 1563 blocks -> 50016 slots, exactly 2 nodes/slot (last few 1).
    const int PB = (N + 63) / 64;

    // ----- ELL build: scan-based radix partition (no global atomics) -----
    const int NBKT = (N + 63) >> 6;                 // 64-node buckets
    const int NSEG = 256;
    int SEG = ((E + NSEG - 1) / NSEG + 3) & ~3;     // int4-aligned segment
    const int SCAN_N = NBKT * 256;
    const int NCH = (SCAN_N + 1023) / 1024;
    // build scratch overlays xwh (packed) and hb (hist/scan) - dead during build
    int* packed    = (int*)xwh;
    int* hist      = (int*)hb;
    int* chunkScan = hist + (size_t)NSEG * NBKT;
    int* chunkTot  = chunkScan + (size_t)NCH * 1024;
    int* chunkBase = chunkTot + NCH;
    bool fast_build = (NBKT <= 2048) && (NCH <= 512) && (N < (1 << 26)) &&
                      ((size_t)E <= (size_t)Na * 32) &&
                      ((size_t)NSEG * NBKT + (size_t)NCH * 1024 + 2 * NCH <= (size_t)Na * 32);

    if (fast_build) {
        k_hist<<<NSEG, 256, 0, stream>>>(dst, hist, E, SEG, NBKT);
        k_scanA<<<NCH, 256, 0, stream>>>(hist, chunkScan, chunkTot, NBKT, SCAN_N);
        k_scanB<<<1, 256, 0, stream>>>(chunkTot, chunkBase, NCH);
        k_scatter_part<<<NSEG, 256, 0, stream>>>(src, dst, chunkScan, chunkBase, packed, E, SEG, NBKT);
        k_ellfill<<<NBKT, 256, 0, stream>>>(packed, chunkScan, chunkBase, ell, cursor, dinv,
                                            CAP, NBKT, N, E);
    } else {
        k_cursor_init<<<NB, 256, 0, stream>>>(cursor, CAP, N);
        const int NCHUNK = 10;
        int cs = (N + NCHUNK - 1) / NCHUNK;
        const int EB4 = (E / 4 + 255) / 256;
        for (int c = 0; c < NCHUNK; ++c) {
            int lo = c * cs, hi = min(N, lo + cs);
            k_fill_ell<<<EB4, 256, 0, stream>>>(src, dst, cursor, ell, E, lo, hi);
        }
        k_deg_dinv<<<NB, 256, 0, stream>>>(cursor, dinv, CAP, N);
    }

    // ----- 3 layers -----
    for (int layer = 0; layer < 3; ++layer) {
        if (layer == 0) {
            gemm2<128, false><<<RB, 256, 0, stream>>>(x, W0, nullptr, dinv, xwh, N);
        } else {
            k_wprime<<<1, 64, 0, stream>>>(Wsp + (size_t)(layer - 1) * 64 * 64, scbuf, shbuf, Wp, bbv);
            gemm2<64, true><<<RB, 256, 0, stream>>>(hb, Wp, bbv, dinv, xwh, N);
        }
        hipMemsetAsync(sums, 0, 128 * sizeof(float), stream);  // sums+sumsq contiguous
        if (layer < 2) {
            k_pull<true><<<PB, 256, 0, stream>>>(cursor, ell, dinv, (const uint4*)xwh,
                                                 b + layer * 64, nullptr, hb,
                                                 sums, sumsq, CAP, N);
        } else {
            k_pull<false><<<PB, 256, 0, stream>>>(cursor, ell, dinv, (const uint4*)xwh,
                                                  b + layer * 64, aggf, nullptr,
                                                  sums, sumsq, CAP, N);
        }
        k_params<<<1, 64, 0, stream>>>(sums, sumsq, alpha + layer * 64, gamma + layer * 64,
                                       beta + layer * 64, scbuf, shbuf, N);
    }
    k_final<<<(n64 + 255) / 256, 256, 0, stream>>>(aggf, scbuf, shbuf, n64);
}